// Round 4
// baseline (85.390 us; speedup 1.0000x reference)
//
#include <hip/hip_runtime.h>

// Problem constants
#define B_ 4
#define E_ 1024
#define S_ 2048
#define H_ 16
#define K_ 1024

#define NCH 32          // scan chunks along S (batch-local)
#define CS  (S_/NCH)    // 64

typedef __bf16 bf16x8 __attribute__((ext_vector_type(8)));
typedef float  f32x4  __attribute__((ext_vector_type(4)));

__device__ __forceinline__ unsigned short f2bf(float f) {
  unsigned u = __float_as_uint(f);
  u += 0x7fffu + ((u >> 16) & 1u);   // round-to-nearest-even
  return (unsigned short)(u >> 16);
}
__device__ __forceinline__ float bf2f(unsigned short h) {
  return __uint_as_float(((unsigned)h) << 16);
}

// ---------------------------------------------------------------------------
// Merged: x (B,E,S) fp32 -> Xt (B,S,E) bf16 transpose  (blockIdx.z < 4)
//       + weight fp32->bf16 conversion                  (blockIdx.z == 4)
// ---------------------------------------------------------------------------
__global__ __launch_bounds__(256)
void tc_kernel(const float* __restrict__ x, unsigned short* __restrict__ xt,
               const float* __restrict__ inw, const float* __restrict__ outw,
               unsigned short* __restrict__ w1, unsigned short* __restrict__ w2)
{
  if (blockIdx.z == 4) {
    // weight conversion: 512 blocks x 256 thr x 4 float4
    const int per = (E_ * E_) / 4;                 // float4s per matrix
    const int fid = blockIdx.y * 32 + blockIdx.x;  // 0..511
#pragma unroll
    for (int k = 0; k < 4; ++k) {
      int i = fid * 1024 + k * 256 + threadIdx.x;  // 0 .. 2*per-1
      const float4* src = (i < per) ? (const float4*)inw : (const float4*)outw;
      unsigned short* dst = (i < per) ? w1 : w2;
      int j = (i < per) ? i : i - per;
      float4 v = src[j];
      ushort4 o;
      o.x = f2bf(v.x); o.y = f2bf(v.y); o.z = f2bf(v.z); o.w = f2bf(v.w);
      *(ushort4*)(dst + (long)j * 4) = o;
    }
    return;
  }

  __shared__ float t[64][65];
  const int b  = blockIdx.z;
  const int e0 = blockIdx.y * 64;
  const int s0 = blockIdx.x * 64;
  const int tx = threadIdx.x & 63, ty = threadIdx.x >> 6;

  const float* xp = x + ((long)b * E_ + e0) * S_ + s0;
#pragma unroll
  for (int r = 0; r < 16; ++r) {
    int row = r * 4 + ty;                          // e-offset within tile
    t[row][tx] = xp[(long)row * S_ + tx];
  }
  __syncthreads();
  unsigned short* xo = xt + ((long)b * S_ + s0) * E_ + e0;
#pragma unroll
  for (int p = 0; p < 2; ++p) {
    int s = p * 32 + (threadIdx.x >> 3);           // s-offset in tile
    int e = (threadIdx.x & 7) * 8;                 // e-offset in tile
    unsigned short v[8];
#pragma unroll
    for (int j = 0; j < 8; ++j) v[j] = f2bf(t[e + j][s]);
    *(ushort4*)(xo + (long)s * E_ + e)     = make_ushort4(v[0], v[1], v[2], v[3]);
    *(ushort4*)(xo + (long)s * E_ + e + 4) = make_ushort4(v[4], v[5], v[6], v[7]);
  }
}

// ---------------------------------------------------------------------------
// 4-phase GEMM: C (8192 x 1024) = A (8192 x 1024) * Bw (1024 x 1024)^T + bias
// BM=256, BN=128, BK=64; 512 thr (8 waves = 2M x 4N); double-buffered LDS
// 96 KiB XOR-swizzled. 16 MFMA per phase (m201 density); one half-tile
// (3 gload insts) staged per phase; uniform vmcnt(6) = 2 half-tiles in
// flight (T3+T4); setprio around MFMA (T5); XCD-aware tiling (T1).
// VARIANT 0: C = Yt bf16 row-major; ALSO computes per-chunk scan partials
//            (fused scan_part) into `part` via lg-group shfl reduction.
// VARIANT 1: C = out fp32 written transposed into (B_,E_,S_).
// ---------------------------------------------------------------------------
#define BB1 49152      // buffer 1 byte offset (48 KiB per buffer)

__device__ __forceinline__ void stage_a(char* smem, const unsigned short* __restrict__ Ab,
                                        int bb, int t, int ks, int tid, int wid) {
#pragma unroll
  for (int j = 0; j < 2; ++j) {
    int chunk = j * 512 + tid;
    int row = chunk >> 2;
    int cb  = (chunk & 3) << 4;
    int cbs = cb ^ (((row >> 1) & 3) << 4);        // inverse(=same) swizzle on source
    const unsigned short* src = Ab + (long)row * K_ + t * 64 + ks * 32 + (cbs >> 1);
    __builtin_amdgcn_global_load_lds(
        (const __attribute__((address_space(1))) void*)src,
        (__attribute__((address_space(3))) void*)(smem + bb + ks * 16384 + j * 8192 + wid * 1024),
        16, 0, 0);
  }
}

__device__ __forceinline__ void stage_b(char* smem, const unsigned short* __restrict__ Bb,
                                        int bb, int t, int ks, int tid, int wid) {
  int row = tid >> 2;                              // 0..127
  int cb  = (tid & 3) << 4;
  int cbs = cb ^ (((row >> 1) & 3) << 4);
  const unsigned short* src = Bb + (long)row * K_ + t * 64 + ks * 32 + (cbs >> 1);
  __builtin_amdgcn_global_load_lds(
      (const __attribute__((address_space(1))) void*)src,
      (__attribute__((address_space(3))) void*)(smem + bb + 32768 + ks * 8192 + wid * 1024),
      16, 0, 0);
}

#define FENCE asm volatile("" ::: "memory")
#define BAR do { FENCE; __builtin_amdgcn_s_barrier(); FENCE; } while (0)
#define VM(n) asm volatile("s_waitcnt vmcnt(" #n ")" ::: "memory")
#define NOWAIT (void)0

// One phase: read frags (prev-VM-protected), stage next half-tile, counted
// vmcnt (protects NEXT phase's reads), barrier, 16 MFMA, barrier.
#define PH(bb, ks, STAGE, WAIT) do {                                        \
    bf16x8 af[8], bfv[2];                                                   \
    _Pragma("unroll")                                                       \
    for (int q = 0; q < 8; ++q) {                                           \
      int row = wm * 128 + q * 16 + lr;                                     \
      int cb = (lg * 16) ^ (((row >> 1) & 3) << 4);                         \
      af[q] = *(const bf16x8*)(smem + (bb) + (ks) * 16384 + row * 64 + cb); \
    }                                                                       \
    _Pragma("unroll")                                                       \
    for (int q = 0; q < 2; ++q) {                                           \
      int row = wn * 32 + q * 16 + lr;                                      \
      int cb = (lg * 16) ^ (((row >> 1) & 3) << 4);                         \
      bfv[q] = *(const bf16x8*)(smem + (bb) + 32768 + (ks) * 8192 + row * 64 + cb); \
    }                                                                       \
    STAGE;                                                                  \
    WAIT;                                                                   \
    BAR;                                                                    \
    asm volatile("s_waitcnt lgkmcnt(0)" ::: "memory");                      \
    __builtin_amdgcn_s_setprio(1);                                          \
    _Pragma("unroll")                                                       \
    for (int q = 0; q < 8; ++q)                                             \
      _Pragma("unroll")                                                     \
      for (int nf = 0; nf < 2; ++nf)                                        \
        acc[q][nf] = __builtin_amdgcn_mfma_f32_16x16x32_bf16(               \
            af[q], bfv[nf], acc[q][nf], 0, 0, 0);                           \
    __builtin_amdgcn_s_setprio(0);                                          \
    BAR;                                                                    \
  } while (0)

template<int VARIANT>
__global__ __launch_bounds__(512, 2)
void gemm4p(const unsigned short* __restrict__ A, const unsigned short* __restrict__ Bw,
            void* __restrict__ Cout, const float* __restrict__ bias,
            const float* __restrict__ mixw, float* __restrict__ part)
{
  extern __shared__ char smem[];
  const int tid  = threadIdx.x;
  const int lane = tid & 63, wid = tid >> 6;
  const int wm = wid >> 2, wn = wid & 3;           // 2M x 4N waves
  const int lr = lane & 15, lg = lane >> 4;

  // T1 XCD-aware tiling: XCD x owns tm in {4x..4x+3} x tn in {0..7}.
  const int bid = blockIdx.x;
  const int xcd = bid & 7;
  const int j8  = bid >> 3;
  const int tm  = (xcd << 2) | (j8 & 3);           // 0..31
  const int tn  = j8 >> 2;                         // 0..7

  const unsigned short* Ab = A  + (long)tm * 256 * K_;
  const unsigned short* Bb = Bw + (long)tn * 128 * K_;

  f32x4 acc[8][2] = {};

  // Prologue: 3 half-tiles = 9 gload insts; VM(6) retires t0.ks0.
  stage_a(smem, Ab, 0,   0, 0, tid, wid);  stage_b(smem, Bb, 0,   0, 0, tid, wid);
  stage_a(smem, Ab, 0,   0, 1, tid, wid);  stage_b(smem, Bb, 0,   0, 1, tid, wid);
  stage_a(smem, Ab, BB1, 1, 0, tid, wid);  stage_b(smem, Bb, BB1, 1, 0, tid, wid);
  VM(6);
  BAR;

  for (int t = 0; t < 14; ++t) {
    const int bb = (t & 1) ? BB1 : 0;
    const int nb = (t & 1) ? 0 : BB1;
    PH(bb, 0, { stage_a(smem, Ab, nb, t + 1, 1, tid, wid);
                stage_b(smem, Bb, nb, t + 1, 1, tid, wid); }, VM(6));
    PH(bb, 1, { stage_a(smem, Ab, bb, t + 2, 0, tid, wid);
                stage_b(smem, Bb, bb, t + 2, 0, tid, wid); }, VM(6));
  }
  // t=14 (buf0), t=15 (buf1): drain VM(6) -> VM(3) -> VM(0).
  PH(0, 0, { stage_a(smem, Ab, BB1, 15, 1, tid, wid);
             stage_b(smem, Bb, BB1, 15, 1, tid, wid); }, VM(6));
  PH(0,   1, NOWAIT, VM(3));
  PH(BB1, 0, NOWAIT, VM(0));
  PH(BB1, 1, NOWAIT, NOWAIT);

  // Epilogue. C/D frag: col = lane&15, row = (lane>>4)*4 + j  [m89/m91]
#pragma unroll
  for (int nf = 0; nf < 2; ++nf) {
    const int c = tn * 128 + wn * 32 + nf * 16 + lr;
    const float bv = bias[c];
    if constexpr (VARIANT == 0) {
      const int h  = c >> 6;                       // head for this channel
      const int bt = tm >> 3;                      // batch
      const int sb = ((tm & 7) << 8) + wm * 128;   // batch-local s of wave base
      float sm0 = 0.f, sm1 = 0.f;
#pragma unroll
      for (int mf = 0; mf < 8; ++mf) {
#pragma unroll
        for (int j = 0; j < 4; ++j) {
          const int sl = sb + mf * 16 + lg * 4 + j;
          float v = acc[mf][nf][j] + bv;
          ((unsigned short*)Cout)[((long)bt * S_ + sl) * E_ + c] = f2bf(v);
          float w = (h < 8) ? v : v * mixw[h * S_ + sl];
          if (mf < 4) sm0 += w; else sm1 += w;
        }
      }
      // reduce over lg group (lanes lg*16+lr, lg=0..3) -> 64-row chunk sums
      sm0 += __shfl_xor(sm0, 16, 64);  sm0 += __shfl_xor(sm0, 32, 64);
      sm1 += __shfl_xor(sm1, 16, 64);  sm1 += __shfl_xor(sm1, 32, 64);
      if (lg == 0) {
        const int ch0 = ((tm & 7) << 2) + wm * 2;  // batch-local chunk of sm0
        part[((long)bt * NCH + ch0)     * E_ + c] = sm0;
        part[((long)bt * NCH + ch0 + 1) * E_ + c] = sm1;
      }
    } else {
#pragma unroll
      for (int mf = 0; mf < 8; ++mf) {
        const int r0 = tm * 256 + wm * 128 + mf * 16 + lg * 4;
        const int s = r0 & (S_ - 1);
        const int b = r0 >> 11;                    // 256-row tile never crosses batch
        float4 v;
        v.x = acc[mf][nf][0] + bv; v.y = acc[mf][nf][1] + bv;
        v.z = acc[mf][nf][2] + bv; v.w = acc[mf][nf][3] + bv;
        *(float4*)((float*)Cout + ((long)b * E_ + c) * S_ + s) = v;
      }
    }
  }
}

// ---------------------------------------------------------------------------
// scan_final: causal prefix combine using chunk partials from GEMM1 epilogue.
//   h < 8 : z[s,c] = mix_w[h,s] * (prior-chunk sums + intra-chunk cumsum)
//   h >= 8: z[s,c] = (prior weighted sums + intra-chunk weighted cumsum)
// ---------------------------------------------------------------------------
__global__ __launch_bounds__(256)
void scan_final(const unsigned short* __restrict__ yt, const float* __restrict__ mixw,
                const float* __restrict__ mixb, const float* __restrict__ part,
                unsigned short* __restrict__ zt)
{
  const int b  = blockIdx.z;
  const int c  = blockIdx.y * 256 + threadIdx.x;
  const int ch = blockIdx.x;
  const int h  = c >> 6;
  float acc = 0.f;
  for (int p = 0; p < ch; ++p) acc += part[((long)b * NCH + p) * E_ + c];
  const unsigned short* yp = yt + ((long)b * S_ + ch * CS) * E_ + c;
  unsigned short*       zp = zt + ((long)b * S_ + ch * CS) * E_ + c;
  const float* mw = mixw + (long)h * S_ + ch * CS;
  const float* mb = mixb + (long)h * S_ + ch * CS;
  if (h < 8) {
    for (int s = 0; s < CS; ++s) {
      acc += bf2f(yp[(long)s * E_]);
      zp[(long)s * E_] = f2bf(fmaf(acc, mw[s], mb[s]));
    }
  } else {
    for (int s = 0; s < CS; ++s) {
      acc += bf2f(yp[(long)s * E_]) * mw[s];
      zp[(long)s * E_] = f2bf(acc + mb[s]);
    }
  }
}

// ---------------------------------------------------------------------------
extern "C" void kernel_launch(void* const* d_in, const int* in_sizes, int n_in,
                              void* d_out, int out_size, void* d_ws, size_t ws_size,
                              hipStream_t stream)
{
  (void)in_sizes; (void)n_in; (void)out_size; (void)ws_size;
  const float* x     = (const float*)d_in[0];
  const float* in_w  = (const float*)d_in[1];
  const float* in_b  = (const float*)d_in[2];
  const float* out_w = (const float*)d_in[3];
  const float* out_b = (const float*)d_in[4];
  const float* mix_w = (const float*)d_in[5];
  const float* mix_b = (const float*)d_in[6];

  char* ws = (char*)d_ws;
  unsigned short* Xt  = (unsigned short*)(ws);                            // 16 MB (reused as Zt)
  unsigned short* Yt  = (unsigned short*)(ws + (size_t)16 * 1024 * 1024); // 16 MB
  unsigned short* W1b = (unsigned short*)(ws + (size_t)32 * 1024 * 1024); // 2 MB
  unsigned short* W2b = (unsigned short*)(ws + (size_t)34 * 1024 * 1024); // 2 MB
  float*          part = (float*)(ws + (size_t)36 * 1024 * 1024);         // 512 KB
  unsigned short* Zt  = Xt;

  hipFuncSetAttribute((const void*)gemm4p<0>, hipFuncAttributeMaxDynamicSharedMemorySize, 98304);
  hipFuncSetAttribute((const void*)gemm4p<1>, hipFuncAttributeMaxDynamicSharedMemorySize, 98304);

  // transpose+convert (z<4: transpose batch z; z==4: weight convert)
  tc_kernel<<<dim3(S_ / 64, E_ / 64, 5), 256, 0, stream>>>(x, Xt, in_w, out_w, W1b, W2b);

  // in_proj + fused scan partials: Yt = Xt * W1b^T + in_b ; part = chunk sums
  gemm4p<0><<<dim3(256), 512, 98304, stream>>>(Xt, W1b, Yt, in_b, mix_w, part);

  scan_final<<<dim3(NCH, E_ / 256, B_), 256, 0, stream>>>(Yt, mix_w, mix_b, part, Zt);

  // out_proj: out(b,e,s) = transposed-write of Zt * W2b^T + out_b
  gemm4p<1><<<dim3(256), 512, 98304, stream>>>(Zt, W2b, d_out, out_b, nullptr, nullptr);
}